// Round 2
// baseline (2072.916 us; speedup 1.0000x reference)
//
#include <hip/hip_runtime.h>

#define NLVL 6
#define NN   32768
#define KFAN 8
#define FDIM 32
#define HDIM 256

typedef __attribute__((ext_vector_type(4))) float f32x4;
typedef __attribute__((ext_vector_type(8))) _Float16 f16x8;
typedef __attribute__((ext_vector_type(4))) unsigned short u16x4;

__device__ __forceinline__ float h2f(unsigned short u) {
    _Float16 h; __builtin_memcpy(&h, &u, 2); return (float)h;
}
__device__ __forceinline__ unsigned short f2h(float f) {
    _Float16 h = (_Float16)f;   // RNE
    unsigned short u; __builtin_memcpy(&u, &h, 2); return u;
}
__device__ __forceinline__ float tanh_fast(float x) {
    float e = __expf(2.0f * x);
    return 1.0f - 2.0f / (e + 1.0f);
}
__device__ __forceinline__ void gload16(const void* g, void* l) {
    __builtin_amdgcn_global_load_lds((const __attribute__((address_space(1))) void*)g,
                                     (__attribute__((address_space(3))) void*)l, 16, 0, 0);
}

// ---------------------------------------------------------------------------
// Generic fp16 B^T GEMM: out = epilogue(A[M,K] @ B[N,K]^T + bias)
// epilogue: v = tanh(acc + bias[col]); if RES v += res[row,col]; store fp16
// (+ optional fp32 store). 128x128 tile, BK=64, 4 waves (2x2 of 64x64).
// LDS tiles XOR-swizzled (T2, st-16B-block): source block pre-permuted at
// global_load_lds time (cb ^ srow), ds_read XORs ((row&7)<<4) on byte addr.
// ---------------------------------------------------------------------------
template<bool RES, bool F32OUT>
__global__ __launch_bounds__(256)
void gemm_bt(const unsigned short* __restrict__ A, int lda,
             const unsigned short* __restrict__ B, int ldb,
             const float* __restrict__ bias,
             const unsigned short* __restrict__ res, int ldr,
             unsigned short* __restrict__ outB, int ldo,
             float* __restrict__ outF,
             int K)
{
    __shared__ __align__(16) unsigned short sA[128 * 64];
    __shared__ __align__(16) unsigned short sB[128 * 64];

    const int tid  = threadIdx.x;
    const int wid  = tid >> 6;
    const int lane = tid & 63;
    const int wr   = wid >> 1, wc = wid & 1;        // wave quadrant (2x2)
    const int brow = blockIdx.x * 128;
    const int bcol = blockIdx.y * 128;
    const int fr   = lane & 15, fq = lane >> 4;     // fragment row / k-group
    const int srow = lane >> 3;                     // staging row within chunk
    const int scol = ((lane & 7) ^ srow) * 8;       // pre-swizzled 16B col-block

    f32x4 acc[4][4] = {};

    for (int k0 = 0; k0 < K; k0 += 64) {
        #pragma unroll
        for (int it = 0; it < 4; ++it) {
            const int c = wid * 4 + it;             // chunk 0..15 (wave-uniform)
            const int r = c * 8 + srow;             // tile row 0..127
            gload16(A + (size_t)(brow + r) * lda + k0 + scol, sA + c * 512);
            gload16(B + (size_t)(bcol + r) * ldb + k0 + scol, sB + c * 512);
        }
        __syncthreads();
        #pragma unroll
        for (int ks = 0; ks < 2; ++ks) {            // two K=32 sub-steps
            f16x8 av[4], bv[4];
            #pragma unroll
            for (int m = 0; m < 4; ++m) {
                const int r = wr * 64 + m * 16 + fr;
                const int b = r * 128 + ((ks * 64 + fq * 16) ^ ((r & 7) << 4));
                av[m] = *(const f16x8*)((const char*)sA + b);
            }
            #pragma unroll
            for (int n = 0; n < 4; ++n) {
                const int r = wc * 64 + n * 16 + fr;
                const int b = r * 128 + ((ks * 64 + fq * 16) ^ ((r & 7) << 4));
                bv[n] = *(const f16x8*)((const char*)sB + b);
            }
            #pragma unroll
            for (int m = 0; m < 4; ++m)
                #pragma unroll
                for (int n = 0; n < 4; ++n)
                    acc[m][n] = __builtin_amdgcn_mfma_f32_16x16x32_f16(av[m], bv[n], acc[m][n], 0, 0, 0);
        }
        __syncthreads();
    }

    // epilogue: C/D layout col = lane&15, row = (lane>>4)*4 + j  [m89-verified]
    #pragma unroll
    for (int m = 0; m < 4; ++m) {
        #pragma unroll
        for (int n = 0; n < 4; ++n) {
            const int col = bcol + wc * 64 + n * 16 + fr;
            const float bb = bias[col];
            #pragma unroll
            for (int j = 0; j < 4; ++j) {
                const int row = brow + wr * 64 + m * 16 + fq * 4 + j;
                float v = acc[m][n][j] + bb;
                v = tanh_fast(v);
                if (RES) v += h2f(res[(size_t)row * ldr + col]);
                outB[(size_t)row * ldo + col] = f2h(v);
                if (F32OUT) outF[(size_t)row * HDIM + col] = v;
            }
        }
    }
}

// ---------------------------------------------------------------------------
// Embed: e = tanh(feats[N,32] @ We[256,32]^T + be) -> fp16 (optionally zero
// second 256 cols for the [e,0] concat; optionally also store fp32 out).
// ---------------------------------------------------------------------------
template<bool ZERO2, bool F32OUT>
__global__ __launch_bounds__(256)
void embed_kernel(const float* __restrict__ feats,
                  const float* __restrict__ We,
                  const float* __restrict__ be,
                  unsigned short* __restrict__ outB, int ldo,
                  float* __restrict__ outF)
{
    __shared__ float sW[256 * 33];   // +1 pad: kills bank conflicts on t*33+k
    __shared__ float sF[16 * 32];
    const int t = threadIdx.x;
    #pragma unroll
    for (int i = 0; i < 32; ++i) {
        int idx = t + 256 * i;
        sW[(idx >> 5) * 33 + (idx & 31)] = We[idx];
    }
    const size_t base = (size_t)blockIdx.x * 16;
    for (int i = t; i < 16 * 32; i += 256) sF[i] = feats[base * 32 + i];
    __syncthreads();

    const float bb = be[t];
    for (int r = 0; r < 16; ++r) {
        float a = bb;
        #pragma unroll
        for (int k = 0; k < 32; ++k) a += sF[r * 32 + k] * sW[t * 33 + k];
        const float v = tanh_fast(a);
        const size_t row = base + r;
        outB[row * ldo + t] = f2h(v);
        if (ZERO2) outB[row * ldo + 256 + t] = 0;
        if (F32OUT) outF[row * HDIM + t] = v;
    }
}

// ---------------------------------------------------------------------------
// Gather-sum: msg[n,:] = sum_{k<8} e[idx[n,k],:]  (fp16 in, fp32 acc, fp16 out)
// ---------------------------------------------------------------------------
__global__ __launch_bounds__(256)
void gather_kernel(const unsigned short* __restrict__ ehalf,
                   const int* __restrict__ idx,
                   unsigned short* __restrict__ msg)
{
    const int n = blockIdx.x;
    const int t = threadIdx.x;
    const int* row = idx + (size_t)n * KFAN;
    float s = 0.f;
    #pragma unroll
    for (int k = 0; k < KFAN; ++k)
        s += h2f(ehalf[(size_t)row[k] * HDIM + t]);
    msg[(size_t)n * HDIM + t] = f2h(s);
}

// ---------------------------------------------------------------------------
// fp32 -> fp16 weight conversion
// ---------------------------------------------------------------------------
__global__ __launch_bounds__(256)
void cvt_kernel(const float* __restrict__ in, unsigned short* __restrict__ out, int n4)
{
    const int i = blockIdx.x * 256 + threadIdx.x;
    if (i >= n4) return;
    const float4 v = ((const float4*)in)[i];
    u16x4 o;
    o[0] = f2h(v.x); o[1] = f2h(v.y); o[2] = f2h(v.z); o[3] = f2h(v.w);
    ((u16x4*)out)[i] = o;
}

// ---------------------------------------------------------------------------
extern "C" void kernel_launch(void* const* d_in, const int* in_sizes, int n_in,
                              void* d_out, int out_size, void* d_ws, size_t ws_size,
                              hipStream_t stream)
{
    const float* feats    = (const float*)d_in[0];
    const int*   pred_idx = (const int*)d_in[1];
    const float* We       = (const float*)d_in[2];
    const float* be       = (const float*)d_in[3];
    const float* rs_W1    = (const float*)d_in[4];
    const float* rs_b1    = (const float*)d_in[5];
    const float* rs_W2    = (const float*)d_in[6];
    const float* rs_b2    = (const float*)d_in[7];
    const float* rs_W3    = (const float*)d_in[8];
    const float* rs_b3    = (const float*)d_in[9];
    const float* rc_W1    = (const float*)d_in[10];
    const float* rc_b1    = (const float*)d_in[11];
    const float* rc_W2    = (const float*)d_in[12];
    const float* rc_b2    = (const float*)d_in[13];
    const float* rc_W3    = (const float*)d_in[14];
    const float* rc_b3    = (const float*)d_in[15];
    float* out = (float*)d_out;

    // ---- workspace layout (fp16 everywhere) ----
    char* ws = (char*)d_ws;
    size_t off = 0;
    auto alloc = [&](size_t bytes) -> unsigned short* {
        unsigned short* p = (unsigned short*)(ws + off);
        off += (bytes + 255) & ~(size_t)255;
        return p;
    };
    unsigned short* rcW1b = alloc((size_t)6 * 512 * 512 * 2);
    unsigned short* rcW2b = alloc((size_t)6 * 512 * 512 * 2);
    unsigned short* rcW3b = alloc((size_t)6 * 256 * 512 * 2);
    unsigned short* rsW1b = alloc((size_t)12 * 256 * 256 * 2);
    unsigned short* rsW2b = alloc((size_t)12 * 256 * 256 * 2);
    unsigned short* rsW3b = alloc((size_t)12 * 256 * 256 * 2);
    unsigned short* xcat  = alloc((size_t)NN * 512 * 2);   // [e, 0] / node h2 reuse
    unsigned short* p0    = alloc((size_t)NN * 512 * 2);   // big h1 / x2cat
    unsigned short* p1    = alloc((size_t)NN * 512 * 2);   // big h2
    unsigned short* Tb    = alloc((size_t)NN * 256 * 2);
    unsigned short* q0    = alloc((size_t)NN * 256 * 2);
    unsigned short* q1    = alloc((size_t)NN * 256 * 2);
    unsigned short* msgb  = alloc((size_t)NN * 256 * 2);
    unsigned short* ebfA  = alloc((size_t)NN * 256 * 2);
    unsigned short* ebfB  = alloc((size_t)NN * 256 * 2);
    (void)ws_size; (void)in_sizes; (void)n_in; (void)out_size;

    // ---- convert weights fp32 -> fp16 ----
    auto cvt = [&](const float* src, unsigned short* dst, int n) {
        int n4 = n / 4;
        cvt_kernel<<<dim3((n4 + 255) / 256), dim3(256), 0, stream>>>(src, dst, n4);
    };
    cvt(rc_W1, rcW1b, 6 * 512 * 512);
    cvt(rc_W2, rcW2b, 6 * 512 * 512);
    cvt(rc_W3, rcW3b, 6 * 256 * 512);
    cvt(rs_W1, rsW1b, 12 * 256 * 256);
    cvt(rs_W2, rsW2b, 12 * 256 * 256);
    cvt(rs_W3, rsW3b, 12 * 256 * 256);

    auto G = [&](const unsigned short* Ap, int Kd, const unsigned short* Bp, int Nout,
                 const float* bp, const unsigned short* rp, int ldr,
                 unsigned short* ob, int ldo, float* of) {
        dim3 grid(NN / 128, Nout / 128);
        if (of)
            gemm_bt<false, true><<<grid, dim3(256), 0, stream>>>(Ap, Kd, Bp, Kd, bp, nullptr, 0, ob, ldo, of, Kd);
        else if (rp)
            gemm_bt<true, false><<<grid, dim3(256), 0, stream>>>(Ap, Kd, Bp, Kd, bp, rp, ldr, ob, ldo, nullptr, Kd);
        else
            gemm_bt<false, false><<<grid, dim3(256), 0, stream>>>(Ap, Kd, Bp, Kd, bp, nullptr, 0, ob, ldo, nullptr, Kd);
    };

    unsigned short* ebp = ebfA;   // embeds[l-1] (fp16)
    unsigned short* ebc = ebfB;   // embeds[l]

    // level 0: e0 = tanh(feats[0] @ We^T + be)
    embed_kernel<false, true><<<dim3(NN / 16), dim3(256), 0, stream>>>(
        feats, We, be, ebp, 256, out);

    for (int l = 1; l < NLVL; ++l) {
        const int d = (l - 1 < 2) ? (l - 1) : 2;
        const float* fl = feats + (size_t)l * NN * FDIM;

        // embed -> xcat[:, :256], zero xcat[:, 256:]
        embed_kernel<true, false><<<dim3(NN / 16), dim3(256), 0, stream>>>(
            fl, We, be, xcat, 512, nullptr);

        // ---- comb branch: e' = tanh(small(9+d, tanh(big(3+d, [e,0])))) ----
        G(xcat, 512, rcW1b + (size_t)(3 + d) * 512 * 512, 512, rc_b1 + (3 + d) * 512, nullptr, 0, p0, 512, nullptr);
        G(p0,   512, rcW2b + (size_t)(3 + d) * 512 * 512, 512, rc_b2 + (3 + d) * 512, xcat, 512,  p1, 512, nullptr);
        G(p1,   512, rcW3b + (size_t)(3 + d) * 256 * 512, 256, rc_b3 + (3 + d) * 256, nullptr, 0, Tb, 256, nullptr);
        G(Tb,   256, rsW1b + (size_t)(9 + d) * 256 * 256, 256, rs_b1 + (9 + d) * 256, nullptr, 0, q0, 256, nullptr);
        G(q0,   256, rsW2b + (size_t)(9 + d) * 256 * 256, 256, rs_b2 + (9 + d) * 256, Tb, 256,   q1, 256, nullptr);
        G(q1,   256, rsW3b + (size_t)(9 + d) * 256 * 256, 256, rs_b3 + (9 + d) * 256, nullptr, 0, p0, 512, nullptr); // e' -> x2cat[:, :256]

        // ---- message branch: r = tanh(small(2d+1, tanh(small(2d, msgs)))) ----
        gather_kernel<<<dim3(NN), dim3(256), 0, stream>>>(
            ebp, pred_idx + (size_t)(l - 1) * NN * KFAN, msgb);
        G(msgb, 256, rsW1b + (size_t)(2 * d) * 256 * 256,     256, rs_b1 + (2 * d) * 256,     nullptr, 0, q0, 256, nullptr);
        G(q0,   256, rsW2b + (size_t)(2 * d) * 256 * 256,     256, rs_b2 + (2 * d) * 256,     msgb, 256,  q1, 256, nullptr);
        G(q1,   256, rsW3b + (size_t)(2 * d) * 256 * 256,     256, rs_b3 + (2 * d) * 256,     nullptr, 0, Tb, 256, nullptr);
        G(Tb,   256, rsW1b + (size_t)(2 * d + 1) * 256 * 256, 256, rs_b1 + (2 * d + 1) * 256, nullptr, 0, q0, 256, nullptr);
        G(q0,   256, rsW2b + (size_t)(2 * d + 1) * 256 * 256, 256, rs_b2 + (2 * d + 1) * 256, Tb, 256,   q1, 256, nullptr);
        G(q1,   256, rsW3b + (size_t)(2 * d + 1) * 256 * 256, 256, rs_b3 + (2 * d + 1) * 256, nullptr, 0, p0 + 256, 512, nullptr); // r -> x2cat[:, 256:]

        // ---- node branch: e = tanh(small(6+d, tanh(big(d, [e', r])))) ----
        G(p0,   512, rcW1b + (size_t)d * 512 * 512, 512, rc_b1 + d * 512, nullptr, 0, p1,   512, nullptr);
        G(p1,   512, rcW2b + (size_t)d * 512 * 512, 512, rc_b2 + d * 512, p0, 512,   xcat, 512, nullptr);
        G(xcat, 512, rcW3b + (size_t)d * 256 * 512, 256, rc_b3 + d * 256, nullptr, 0, Tb,  256, nullptr);
        G(Tb,   256, rsW1b + (size_t)(6 + d) * 256 * 256, 256, rs_b1 + (6 + d) * 256, nullptr, 0, q0, 256, nullptr);
        G(q0,   256, rsW2b + (size_t)(6 + d) * 256 * 256, 256, rs_b2 + (6 + d) * 256, Tb, 256,   q1, 256, nullptr);
        G(q1,   256, rsW3b + (size_t)(6 + d) * 256 * 256, 256, rs_b3 + (6 + d) * 256, nullptr, 0, ebc, 256,
          out + (size_t)l * NN * HDIM);

        unsigned short* tmp = ebp; ebp = ebc; ebc = tmp;
    }
}